// Round 3
// baseline (118.107 us; speedup 1.0000x reference)
//
#include <hip/hip_runtime.h>
#include <hip/hip_bf16.h>

typedef short bf16x8 __attribute__((ext_vector_type(8)));
typedef float f32x4  __attribute__((ext_vector_type(4)));

__device__ __forceinline__ unsigned short f2bf(float f) {
    union { float f; unsigned int u; } v; v.f = f;
    unsigned int u = v.u;
    u += 0x7FFFu + ((u >> 16) & 1u);   // round-to-nearest-even
    return (unsigned short)(u >> 16);
}

__device__ __forceinline__ f32x4 mfma_bf16(bf16x8 a, bf16x8 b, f32x4 c) {
    return __builtin_amdgcn_mfma_f32_16x16x32_bf16(a, b, c, 0, 0, 0);
}

// ---------------- prep: transpose + bf16-convert four 256x256 weights ----------------
// dst layout: WT[n][k] = W[k][n], bf16, row-major [256][256]; 4 matrices back to back.
__global__ __launch_bounds__(256) void prep_weights(
    const float* __restrict__ wq, const float* __restrict__ wk,
    const float* __restrict__ wv, const float* __restrict__ wo,
    unsigned short* __restrict__ wt)
{
    __shared__ float tile[64][65];
    const int bx  = blockIdx.x;        // 0..63
    const int mat = bx >> 4;
    const int t   = bx & 15;
    const int tn  = t >> 2, tk = t & 3;   // 64x64 tile coords
    const float* src = (mat == 0) ? wq : (mat == 1) ? wk : (mat == 2) ? wv : wo;
    unsigned short* dst = wt + mat * 65536;
    const int tid = threadIdx.x;
#pragma unroll
    for (int j = 0; j < 16; ++j) {
        int idx = tid + 256 * j;
        int r = idx >> 6, c = idx & 63;
        tile[r][c] = src[(tk * 64 + r) * 256 + tn * 64 + c];
    }
    __syncthreads();
#pragma unroll
    for (int j = 0; j < 16; ++j) {
        int idx = tid + 256 * j;
        int r = idx >> 6, c = idx & 63;
        dst[(tn * 64 + r) * 256 + tk * 64 + c] = f2bf(tile[c][r]);
    }
}

// ---------------- fused window attention ----------------
// grid = 1024 (= 16 b * 64 h), block = 512 (8 waves). Each WG owns 64 tokens (one width row).
// wave w computes cols [32w,32w+32) of Q/K/V (== head w), then attention for head w,
// then cols [32w,32w+32) of the output projection.
#define XS_STRIDE 264   // 256 + 8 pad shorts -> 16B-aligned rows, 2-way banks only
#define PV_STRIDE 72    // 64 + 8 pad shorts -> 16B-aligned rows, 2-way banks only

__global__ __launch_bounds__(512, 1) void win_attn(
    const float* __restrict__ x,
    const unsigned short* __restrict__ wt,   // WqT,WkT,WvT,WoT each 256*256 bf16
    const float* __restrict__ bo,
    float* __restrict__ out)                 // f32 output
{
    __shared__ unsigned short lds[73728];    // 144 KiB
    unsigned short* Xs  = lds;               // [64][264]
    unsigned short* Qs  = lds + 16896;       // [64][264]
    unsigned short* Ks  = lds + 33792;       // [64][264]
    unsigned short* Vst = lds + 50688;       // [256][72]  (V transposed: [d][token])
    unsigned short* Os  = lds;               // [64][264]  reuses Xs (dead after phase 1)

    const int tid  = threadIdx.x;
    const int wid  = tid >> 6;               // 0..7 (= head, = 32-col slice)
    const int lane = tid & 63;
    const int l15  = lane & 15;
    const int g    = lane >> 4;              // 0..3
    // wave-private P buffer [64][72]; waves 0-6 overlay Qs/Ks (dead by then), wave 7 after Vst
    unsigned short* Pbuf = (wid < 7) ? (lds + 16896 + wid * 4608) : (lds + 69120);

    const long long base_tok = (long long)blockIdx.x * 64;
    const float* xblk = x + base_tok * 256;

    // ---- phase 0: stage x row-block as bf16 in LDS ----
#pragma unroll
    for (int i = 0; i < 8; ++i) {
        int p   = tid + i * 512;             // float4 index, 0..4095
        int tok = p >> 6;
        int col = (p & 63) * 4;
        float4 v = reinterpret_cast<const float4*>(xblk)[p];
        ushort4 h;
        h.x = f2bf(v.x); h.y = f2bf(v.y); h.z = f2bf(v.z); h.w = f2bf(v.w);
        *reinterpret_cast<ushort4*>(&Xs[tok * XS_STRIDE + col]) = h;
    }
    __syncthreads();

    // ---- phase 1: Q,K,V = Xs @ W (per wave: all 64 rows, 32 cols) ----
    for (int mat = 0; mat < 3; ++mat) {
        const unsigned short* W = wt + mat * 65536;
        f32x4 acc[4][2] = {};
#pragma unroll
        for (int kk = 0; kk < 8; ++kk) {
            bf16x8 a[4], b[2];
#pragma unroll
            for (int mi = 0; mi < 4; ++mi)
                a[mi] = *reinterpret_cast<const bf16x8*>(&Xs[(mi * 16 + l15) * XS_STRIDE + kk * 32 + g * 8]);
#pragma unroll
            for (int ni = 0; ni < 2; ++ni)
                b[ni] = *reinterpret_cast<const bf16x8*>(&W[(wid * 32 + ni * 16 + l15) * 256 + kk * 32 + g * 8]);
#pragma unroll
            for (int mi = 0; mi < 4; ++mi)
#pragma unroll
                for (int ni = 0; ni < 2; ++ni)
                    acc[mi][ni] = mfma_bf16(a[mi], b[ni], acc[mi][ni]);
        }
        if (mat == 2) {          // V stored transposed: Vst[d][token]
#pragma unroll
            for (int mi = 0; mi < 4; ++mi)
#pragma unroll
                for (int ni = 0; ni < 2; ++ni)
#pragma unroll
                    for (int r = 0; r < 4; ++r)
                        Vst[(wid * 32 + ni * 16 + l15) * PV_STRIDE + mi * 16 + g * 4 + r] = f2bf(acc[mi][ni][r]);
        } else {
            unsigned short* Dst = (mat == 0) ? Qs : Ks;
#pragma unroll
            for (int mi = 0; mi < 4; ++mi)
#pragma unroll
                for (int ni = 0; ni < 2; ++ni)
#pragma unroll
                    for (int r = 0; r < 4; ++r)
                        Dst[(mi * 16 + g * 4 + r) * XS_STRIDE + wid * 32 + ni * 16 + l15] = f2bf(acc[mi][ni][r]);
        }
    }
    __syncthreads();

    // ---- phase 2a: S = Q_n @ K_n^T (M=64,N=64,K=32), head n = wid ----
    f32x4 sacc[4][4] = {};
    {
        bf16x8 qa[4], kb[4];
#pragma unroll
        for (int i = 0; i < 4; ++i) {
            qa[i] = *reinterpret_cast<const bf16x8*>(&Qs[(i * 16 + l15) * XS_STRIDE + wid * 32 + g * 8]);
            kb[i] = *reinterpret_cast<const bf16x8*>(&Ks[(i * 16 + l15) * XS_STRIDE + wid * 32 + g * 8]);
        }
#pragma unroll
        for (int mi = 0; mi < 4; ++mi)
#pragma unroll
            for (int ni = 0; ni < 4; ++ni)
                sacc[mi][ni] = mfma_bf16(qa[mi], kb[ni], sacc[mi][ni]);
    }
    __syncthreads();   // all Qs/Ks reads done before P overlays them

    // ---- phase 2b: register softmax (rows spread over 16-lane groups) + write P ----
    constexpr float kC = 0.25501817419392105f;  // (1/sqrt(32)) * log2(e)
#pragma unroll
    for (int mi = 0; mi < 4; ++mi) {
#pragma unroll
        for (int r = 0; r < 4; ++r) {
            float m = fmaxf(fmaxf(sacc[mi][0][r], sacc[mi][1][r]),
                            fmaxf(sacc[mi][2][r], sacc[mi][3][r]));
            m = fmaxf(m, __shfl_xor(m, 1));
            m = fmaxf(m, __shfl_xor(m, 2));
            m = fmaxf(m, __shfl_xor(m, 4));
            m = fmaxf(m, __shfl_xor(m, 8));
            float p0 = exp2f((sacc[mi][0][r] - m) * kC);
            float p1 = exp2f((sacc[mi][1][r] - m) * kC);
            float p2 = exp2f((sacc[mi][2][r] - m) * kC);
            float p3 = exp2f((sacc[mi][3][r] - m) * kC);
            float sum = p0 + p1 + p2 + p3;
            sum += __shfl_xor(sum, 1);
            sum += __shfl_xor(sum, 2);
            sum += __shfl_xor(sum, 4);
            sum += __shfl_xor(sum, 8);
            float inv = 1.0f / sum;
            int q = mi * 16 + g * 4 + r;
            Pbuf[q * PV_STRIDE +  0 + l15] = f2bf(p0 * inv);
            Pbuf[q * PV_STRIDE + 16 + l15] = f2bf(p1 * inv);
            Pbuf[q * PV_STRIDE + 32 + l15] = f2bf(p2 * inv);
            Pbuf[q * PV_STRIDE + 48 + l15] = f2bf(p3 * inv);
        }
    }
    __syncthreads();   // ensures P writes land before P reads (and uniform schedule)

    // ---- phase 2c: O_n = P @ V_n (M=64,N=32,K=64) ----
    f32x4 oacc[4][2] = {};
#pragma unroll
    for (int kk = 0; kk < 2; ++kk) {
        bf16x8 pa[4], vb[2];
#pragma unroll
        for (int mi = 0; mi < 4; ++mi)
            pa[mi] = *reinterpret_cast<const bf16x8*>(&Pbuf[(mi * 16 + l15) * PV_STRIDE + kk * 32 + g * 8]);
#pragma unroll
        for (int ni = 0; ni < 2; ++ni)
            vb[ni] = *reinterpret_cast<const bf16x8*>(&Vst[(wid * 32 + ni * 16 + l15) * PV_STRIDE + kk * 32 + g * 8]);
#pragma unroll
        for (int mi = 0; mi < 4; ++mi)
#pragma unroll
            for (int ni = 0; ni < 2; ++ni)
                oacc[mi][ni] = mfma_bf16(pa[mi], vb[ni], oacc[mi][ni]);
    }
    // merged attention output Os[token][head*32+d] (region disjoint from live P/Vst)
#pragma unroll
    for (int mi = 0; mi < 4; ++mi)
#pragma unroll
        for (int ni = 0; ni < 2; ++ni)
#pragma unroll
            for (int r = 0; r < 4; ++r)
                Os[(mi * 16 + g * 4 + r) * XS_STRIDE + wid * 32 + ni * 16 + l15] = f2bf(oacc[mi][ni][r]);
    __syncthreads();

    // ---- phase 3: Y = Os @ Wo + bo, f32 store ----
    {
        const unsigned short* WO = wt + 3 * 65536;
        f32x4 yacc[4][2] = {};
#pragma unroll
        for (int kk = 0; kk < 8; ++kk) {
            bf16x8 a[4], b[2];
#pragma unroll
            for (int mi = 0; mi < 4; ++mi)
                a[mi] = *reinterpret_cast<const bf16x8*>(&Os[(mi * 16 + l15) * XS_STRIDE + kk * 32 + g * 8]);
#pragma unroll
            for (int ni = 0; ni < 2; ++ni)
                b[ni] = *reinterpret_cast<const bf16x8*>(&WO[(wid * 32 + ni * 16 + l15) * 256 + kk * 32 + g * 8]);
#pragma unroll
            for (int mi = 0; mi < 4; ++mi)
#pragma unroll
                for (int ni = 0; ni < 2; ++ni)
                    yacc[mi][ni] = mfma_bf16(a[mi], b[ni], yacc[mi][ni]);
        }
#pragma unroll
        for (int mi = 0; mi < 4; ++mi) {
#pragma unroll
            for (int ni = 0; ni < 2; ++ni) {
                int col = wid * 32 + ni * 16 + l15;
                float bv = bo[col];
#pragma unroll
                for (int r = 0; r < 4; ++r) {
                    int row = mi * 16 + g * 4 + r;
                    out[(base_tok + row) * 256 + col] = yacc[mi][ni][r] + bv;
                }
            }
        }
    }
}

extern "C" void kernel_launch(void* const* d_in, const int* in_sizes, int n_in,
                              void* d_out, int out_size, void* d_ws, size_t ws_size,
                              hipStream_t stream) {
    const float* x  = (const float*)d_in[0];
    const float* wq = (const float*)d_in[1];
    const float* wk = (const float*)d_in[2];
    const float* wv = (const float*)d_in[3];
    const float* wo = (const float*)d_in[4];
    const float* bo = (const float*)d_in[5];
    unsigned short* wt = (unsigned short*)d_ws;      // 4 * 256*256 bf16 = 512 KiB
    float* out = (float*)d_out;                      // f32 output

    prep_weights<<<64, 256, 0, stream>>>(wq, wk, wv, wo, wt);
    win_attn<<<1024, 512, 0, stream>>>(x, wt, bo, out);
}